// Round 10
// baseline (260.238 us; speedup 1.0000x reference)
//
#include <hip/hip_runtime.h>
#include <hip/hip_bf16.h>

typedef unsigned int u32;
typedef unsigned short u16;
typedef __attribute__((ext_vector_type(8))) short short8;   // 8 bf16 (4 VGPRs)
typedef __attribute__((ext_vector_type(4))) float f32x4;    // 4 fp32 acc

#define MFMA(a,b,c) __builtin_amdgcn_mfma_f32_16x16x32_bf16(a,b,c,0,0,0)

// ---------------- helpers ----------------
__device__ __forceinline__ float bf2f(u16 u){ return __uint_as_float(((u32)u)<<16); }
__device__ __forceinline__ float lo16(u32 w){ return __uint_as_float(w<<16); }
__device__ __forceinline__ float hi16(u32 w){ return __uint_as_float(w & 0xffff0000u); }
__device__ __forceinline__ u16 f2b(float x){ __hip_bfloat16 h=__float2bfloat16(x); return *(u16*)&h; }
__device__ __forceinline__ u32 pack2(float a, float b){ return (u32)f2b(a) | ((u32)f2b(b)<<16); }

// canonical f32 weight pool: element offsets (verified R5)
#define O_Wf1 0
#define O_bf1 1024
#define O_Wf2 1280
#define O_bf2 66816
#define O_Wu1 67072
#define O_bu1 68096
#define O_Wu2 68352
#define O_bu2 133888
#define O_remb 134144
#define O_Wq 134656
#define O_bq 200192
#define O_Wk 200448
#define O_bk 265984
#define O_Wv 266240
#define O_bv 331776
#define O_Wo 332032
#define O_bo 397568
#define O_ag 397824
#define O_ab 398080
#define O_lg 398336
#define O_lb 399616
#define O_Wc1 400896
#define O_bc1 728576
#define O_Wc2 728832
#define O_bc2 729088
#define TOTW 729089
#define NCONV 2849   // ceil(TOTW/256)

static __device__ const int c_off[26] = {
  0,1024,1280,66816,67072,68096,68352,133888,134144,134656,200192,200448,
  265984,266240,331776,332032,397568,397824,398080,398336,399616,400896,
  728576,728832,729088,729089};

struct WPar { const void* src[25]; const u32* traj; float* dst; };

__device__ __forceinline__ int detect_bf16(const u32* traj){
  int inr = 0;
#pragma unroll 1
  for(int i=0;i<64;i++){
    u32 e = (traj[i]>>7) & 0xffu;
    inr += (e >= 0x58u && e <= 0x9au) ? 1 : 0;
  }
  return (inr==64) ? 1 : 0;
}

// ---------------- K0: conv (weights->f32) ∥ pool+mask, block-partitioned ----------------
__global__ __launch_bounds__(256) void k_init(WPar p, const u32* __restrict__ mraw,
                                              float* __restrict__ pooled, int* __restrict__ maskI){
  __shared__ int fl;
  if(threadIdx.x==0) fl = detect_bf16(p.traj);
  __syncthreads();
  int mode = fl;
  if(blockIdx.x < NCONV){
    int g = blockIdx.x*256 + threadIdx.x;
    if(g >= TOTW) return;
    int t = 0;
#pragma unroll 1
    for(int i=1;i<25;i++) if(g >= c_off[i]) t = i;
    int j = g - c_off[t];
    float v = mode ? bf2f(((const u16*)p.src[t])[j]) : ((const float*)p.src[t])[j];
    p.dst[g] = v;
  } else {
    int t = (blockIdx.x - NCONV)*256 + threadIdx.x;
    int b = t>>8, r = t&255;
    float s = 0.f;
    if(mode){
      const u16* tp = (const u16*)p.traj + (size_t)b*12800 + r;
#pragma unroll 1
      for(int l=0;l<50;l++) s += bf2f(tp[l*256]);
    } else {
      const float* tp = (const float*)p.traj + (size_t)b*12800 + r;
#pragma unroll 1
      for(int l=0;l<50;l++) s += tp[l*256];
    }
    pooled[t] = s * 0.02f;
    if(t < 16384){
      bool isByte = false;
#pragma unroll
      for(int w=0;w<16;w++) isByte |= (mraw[w] > 1u);
      int v;
      if(isByte){ u32 w = mraw[t>>2]; v = (int)((w >> ((t&3)*8)) & 0xffu); }
      else      { v = (int)mraw[t]; }
      maskI[t] = (v!=0) ? 1 : 0;
    }
  }
}

// ---------------- K1: merged WF-dependent prep: h(4096) | trans(96) | transc(64) | prep(256) ----------------
static __device__ const int t_src[6] = {O_Wf2, O_Wu2, O_Wq, O_Wk, O_Wv, O_Wo};
__global__ __launch_bounds__(256) void k_wprep(const float* __restrict__ WF, const float* __restrict__ pooled,
                                               const int* __restrict__ roles, u32* __restrict__ hb,
                                               u16* __restrict__ WT, u16* __restrict__ WTC,
                                               float* __restrict__ UG){
  __shared__ float tl[64][65];
  int bid = blockIdx.x;
  int t = threadIdx.x;
  if(bid < 4096){
    // ---- enc layer 1 -> h bf16 [16384][256] ----
    int g = bid*256 + t;
    int r = g>>6, e0 = (g&63)*4;
    float4 pl = *(const float4*)(pooled + r*4);
    int role = roles[r];
    const float* W1 = WF + (role ? O_Wu1 : O_Wf1);
    const float* b1 = WF + (role ? O_bu1 : O_bf1);
    float h[4];
#pragma unroll
    for(int c=0;c<4;c++){
      int e = e0+c;
      float v = b1[e] + pl.x*W1[e] + pl.y*W1[256+e] + pl.z*W1[512+e] + pl.w*W1[768+e];
      h[c] = fmaxf(v, 0.f);
    }
    hb[(r*256+e0)>>1]     = pack2(h[0],h[1]);
    hb[((r*256+e0)>>1)+1] = pack2(h[2],h[3]);
    return;
  }
  if(bid < 4192){
    // ---- transpose f32 -> bf16 WT in MFMA-fragment-major order ----
    int b2 = bid - 4096;
    int mat = b2 >> 4, tile = b2 & 15;
    int kt = (tile>>2)*64, nt = (tile&3)*64;
    int i = t>>2, c4 = (t&3)*16;
    const float* src = WF + t_src[mat] + (kt+i)*256 + nt + c4;
#pragma unroll
    for(int c=0;c<16;c+=4) *(float4*)&tl[i][c4+c] = *(const float4*)(src + c);
    __syncthreads();
    int n = nt + i;
    int tile_n = n >> 4, nl = n & 15;
    int ks = (kt + c4) >> 5;
    u16* base = WT + mat*65536;
#pragma unroll
    for(int h=0; h<2; h++){
      int quad = ((c4 + h*8) >> 3) & 3;
      short8 v;
#pragma unroll
      for(int j=0;j<8;j++) v[j] = (short)f2b(tl[c4 + h*8 + j][i]);
      *(short8*)(base + ((tile_n*8 + ks)*64 + quad*16 + nl)*8) = v;
    }
    return;
  }
  if(bid < 4256){
    // ---- WTC (lg-folded, d-combined Wc1^T, K=1024) fragment-major ----
    int b2 = bid - 4192;
    int seg = b2 >> 4, tile = b2 & 15;
    int jt = (tile>>2)*64, nt = (tile&3)*64;
    int i = t>>2, c4 = (t&3)*16;
    int j = jt + i;
#pragma unroll 1
    for(int c=0;c<16;c++){
      int n = nt + c4 + c;
      float v;
      if(seg==0)      v = WF[O_lg+j]*WF[O_Wc1 + j*256 + n] + WF[O_lg+768+j]*WF[O_Wc1 + (768+j)*256 + n];
      else if(seg==1) v = WF[O_lg+256+j]*WF[O_Wc1+(256+j)*256+n] - WF[O_lg+768+j]*WF[O_Wc1+(768+j)*256+n];
      else if(seg==2) v = WF[O_lg+512+j]*WF[O_Wc1+(512+j)*256+n];
      else            v = WF[O_lg+1024+j]*WF[O_Wc1+(1024+j)*256+n];
      tl[i][c4+c] = v;
    }
    __syncthreads();
    int n = nt + i;
    int tile_n = n >> 4, nl = n & 15;
    int kbase = seg*256 + jt + c4;
    int ks = kbase >> 5;
#pragma unroll
    for(int h=0; h<2; h++){
      int quad = ((kbase + h*8) >> 3) & 3;
      short8 v;
#pragma unroll
      for(int jj=0;jj<8;jj++) v[jj] = (short)f2b(tl[c4 + h*8 + jj][i]);
      *(short8*)(WTC + ((tile_n*32 + ks)*64 + quad*16 + nl)*8) = v;
    }
    return;
  }
  {
    // ---- U[n] / G[n] for classifier epilogue ----
    __shared__ float ru[4], rg[4];
    int n = bid - 4256;
    float u = 0.f, g = 0.f;
#pragma unroll
    for(int j=0;j<5;j++){
      int m = t + j*256;
      float w = WF[O_Wc1 + m*256 + n];
      u = fmaf(WF[O_lb+m], w, u);
      g = fmaf(WF[O_lg+m], w, g);
    }
#pragma unroll
    for(int o=32;o>0;o>>=1){ u += __shfl_xor(u,o,64); g += __shfl_xor(g,o,64); }
    int wv = t>>6;
    if((t&63)==0){ ru[wv]=u; rg[wv]=g; }
    __syncthreads();
    if(t==0){
      UG[n]     = ru[0]+ru[1]+ru[2]+ru[3] + WF[O_bc1+n];
      UG[256+n] = rg[0]+rg[1]+rg[2]+rg[3];
    }
  }
}

// ---------------- shared GEMM pieces (BM=32, K=256, LDS stride 264) ----------------
__device__ __forceinline__ void stageA256(const u16* __restrict__ A, long row0, u16* As){
  int t = threadIdx.x;
  int r = t >> 3, c0 = (t & 7) * 32;
  const u16* src = A + (row0 + r)*256 + c0;
  u16* dst = As + r*264 + c0;
#pragma unroll
  for(int i=0;i<4;i++) *(short8*)(dst + i*8) = *(const short8*)(src + i*8);
}

// B in fragment-major order: frag(tile,ks) at ((tile*8+ks)*64 + lane)*8 — 1KB coalesced/wave
__device__ __forceinline__ void mmK256(const u16* As, const u16* __restrict__ WT, int wv,
                                       int colL, int quad, int lane, f32x4 acc[2][4]){
#pragma unroll
  for(int ks=0; ks<8; ks++){
    short8 a0 = *(short8*)(As + colL*264 + ks*32 + quad*8);
    short8 a1 = *(short8*)(As + (colL+16)*264 + ks*32 + quad*8);
#pragma unroll
    for(int ct=0; ct<4; ct++){
      short8 b = *(const short8*)(WT + (((wv*4+ct)*8 + ks)*64 + lane)*8);
      acc[0][ct] = MFMA(a0, b, acc[0][ct]);
      acc[1][ct] = MFMA(a1, b, acc[1][ct]);
    }
  }
}

// ---------------- K2: enc layer 2 dual GEMM + select + mask + remb -> x0 bf16 ----------------
__global__ __launch_bounds__(256,2) void k_enc2(const float* __restrict__ WF, const u16* __restrict__ hb,
                                                const int* __restrict__ roles, const int* __restrict__ maskI,
                                                const u16* __restrict__ WT2F, const u16* __restrict__ WT2U,
                                                u16* __restrict__ x0b){
  __shared__ u16 As[32*264];
  __shared__ int roleS[32], maskS[32];
  long row0 = (long)blockIdx.x*32;
  int t = threadIdx.x;
  stageA256(hb, row0, As);
  if(t<32){ roleS[t]=roles[row0+t]; maskS[t]=maskI[row0+t]; }
  __syncthreads();
  int lane = t & 63, wv = t >> 6;
  int colL = lane & 15, quad = lane >> 4;
  f32x4 accF[2][4] = {};
  f32x4 accU[2][4] = {};
  mmK256(As, WT2F, wv, colL, quad, lane, accF);
  mmK256(As, WT2U, wv, colL, quad, lane, accU);
#pragma unroll
  for(int ct=0; ct<4; ct++){
    int col = wv*64 + ct*16 + colL;
    float bfc = WF[O_bf2+col], buc = WF[O_bu2+col];
    float r0c = WF[O_remb+col], r1c = WF[O_remb+256+col];
#pragma unroll
    for(int rt=0; rt<2; rt++)
#pragma unroll
    for(int reg=0; reg<4; reg++){
      int row = rt*16 + quad*4 + reg;
      float vf = accF[rt][ct][reg] + bfc;
      float vu = accU[rt][ct][reg] + buc;
      int ro = roleS[row];
      float v = ro ? vu : vf;
      v = maskS[row] ? v : 0.f;
      v += ro ? r1c : r0c;
      x0b[(size_t)(row0+row)*256 + col] = f2b(v);
    }
  }
}

// ---------------- K3: qkv GEMM (grid.y selects q/k/v) ----------------
static __device__ const int qkv_b[3] = {O_bq, O_bk, O_bv};
__global__ __launch_bounds__(256,2) void k_qkv(const float* __restrict__ WF, const u16* __restrict__ x0b,
                                               const u16* __restrict__ WTQ, u16* __restrict__ qout){
  __shared__ u16 As[32*264];
  long row0 = (long)blockIdx.x*32;
  int y = blockIdx.y;
  stageA256(x0b, row0, As);
  __syncthreads();
  int t = threadIdx.x;
  int lane = t & 63, wv = t >> 6;
  int colL = lane & 15, quad = lane >> 4;
  f32x4 acc[2][4] = {};
  mmK256(As, WTQ + y*65536, wv, colL, quad, lane, acc);
  u16* outp = qout + (size_t)y*4194304;
  int bo = qkv_b[y];
#pragma unroll
  for(int ct=0; ct<4; ct++){
    int col = wv*64 + ct*16 + colL;
    float bc = WF[bo+col];
#pragma unroll
    for(int rt=0; rt<2; rt++)
#pragma unroll
    for(int reg=0; reg<4; reg++){
      int row = rt*16 + quad*4 + reg;
      outp[(size_t)(row0+row)*256 + col] = f2b(acc[rt][ct][reg] + bc);
    }
  }
}

// ---------------- K4: MFMA attention (verified R1: 286->261) ----------------
#define VT_STR 72   // u16 stride, multiple of 8 -> 16B-aligned b128 reads
__global__ __launch_bounds__(256,2) void k_attn6(const u16* __restrict__ qb, const u16* __restrict__ kb,
                                                 const u16* __restrict__ vb, const int* __restrict__ maskI,
                                                 u16* __restrict__ ctxb){
  __shared__ u16 Vt[64*VT_STR];     // V^T: Vt[d][j]
  __shared__ u16 Pp[64*VT_STR];     // exp(S-m) bf16: Pp[q][j]; later reused per-wave for ctx repack
  __shared__ int maskS[64];
  const int t = threadIdx.x;
  const int b = blockIdx.x, h = blockIdx.y;
  const int lane = t & 63;
  const int wv = t >> 6;
  const int colL = lane & 15, quad = lane >> 4;

  // ---- stage V^T + mask (all threads) ----
  {
    int j  = t >> 2;                 // 0..63 key row
    int dc = (t & 3) * 16;           // 16-wide d chunk
    const u16* vr = vb + (size_t)(b*64 + j)*256 + h*64 + dc;
    uint4 w0 = *(const uint4*)(vr);
    uint4 w1 = *(const uint4*)(vr + 8);
    u32 wd[8] = {w0.x,w0.y,w0.z,w0.w,w1.x,w1.y,w1.z,w1.w};
#pragma unroll
    for(int i=0;i<8;i++){
      u32 w = wd[i];
      Vt[(dc + 2*i    )*VT_STR + j] = (u16)(w & 0xffffu);
      Vt[(dc + 2*i + 1)*VT_STR + j] = (u16)(w >> 16);
    }
    if(t < 64) maskS[t] = maskI[b*64 + t];
  }

  // ---- QK^T: 8 MFMAs, operands straight from global ----
  f32x4 acc[4] = {};                 // acc[tj]: S[wv*16+quad*4+reg][tj*16+colL]
  {
    const u16* qrow = qb + (size_t)(b*64 + wv*16 + colL)*256 + h*64 + quad*8;
#pragma unroll
    for(int ks=0; ks<2; ks++){
      short8 a = *(const short8*)(qrow + ks*32);
#pragma unroll
      for(int tj=0; tj<4; tj++){
        short8 bf = *(const short8*)(kb + (size_t)(b*64 + tj*16 + colL)*256 + h*64 + ks*32 + quad*8);
        acc[tj] = MFMA(a, bf, acc[tj]);
      }
    }
  }

  __syncthreads();                   // Vt + maskS ready

  // ---- scale + mask + softmax (rows spread over the 16 lanes sharing quad) ----
#pragma unroll
  for(int tj=0; tj<4; tj++){
    int mk = maskS[tj*16 + colL];
#pragma unroll
    for(int reg=0; reg<4; reg++)
      acc[tj][reg] = mk ? acc[tj][reg]*0.125f : -1e9f;
  }
  float m[4], sum[4];
#pragma unroll
  for(int reg=0; reg<4; reg++){
    float v = fmaxf(fmaxf(acc[0][reg],acc[1][reg]), fmaxf(acc[2][reg],acc[3][reg]));
    v = fmaxf(v, __shfl_xor(v,1,64));
    v = fmaxf(v, __shfl_xor(v,2,64));
    v = fmaxf(v, __shfl_xor(v,4,64));
    v = fmaxf(v, __shfl_xor(v,8,64));
    m[reg] = v;
    sum[reg] = 0.f;
  }
#pragma unroll
  for(int tj=0; tj<4; tj++)
#pragma unroll
  for(int reg=0; reg<4; reg++){
    float e = __expf(acc[tj][reg] - m[reg]);
    acc[tj][reg] = e;
    sum[reg] += e;
  }
#pragma unroll
  for(int reg=0; reg<4; reg++){
    float v = sum[reg];
    v += __shfl_xor(v,1,64); v += __shfl_xor(v,2,64);
    v += __shfl_xor(v,4,64); v += __shfl_xor(v,8,64);
    sum[reg] = v;
  }

  // ---- P (unnormalized) -> bf16 -> own wave's LDS strip (wave-local, no barrier) ----
#pragma unroll
  for(int tj=0; tj<4; tj++)
#pragma unroll
  for(int reg=0; reg<4; reg++)
    Pp[(wv*16 + quad*4 + reg)*VT_STR + tj*16 + colL] = f2b(acc[tj][reg]);

  // ---- PV: 8 MFMAs; A = P strip (b128), B = Vt rows (b128) ----
  f32x4 o[4] = {};                   // o[dt]: ctx[wv*16+quad*4+reg][dt*16+colL]
  {
    const u16* prow = Pp + (wv*16 + colL)*VT_STR + quad*8;
#pragma unroll
    for(int ks=0; ks<2; ks++){
      short8 a = *(const short8*)(prow + ks*32);
#pragma unroll
      for(int dt=0; dt<4; dt++){
        short8 bf = *(const short8*)(Vt + (dt*16 + colL)*VT_STR + ks*32 + quad*8);
        o[dt] = MFMA(a, bf, o[dt]);
      }
    }
  }

  // ---- normalize (f32) + repack via own LDS strip for coalesced stores ----
  float inv[4];
#pragma unroll
  for(int reg=0; reg<4; reg++) inv[reg] = 1.f/sum[reg];
#pragma unroll
  for(int dt=0; dt<4; dt++)
#pragma unroll
  for(int reg=0; reg<4; reg++)
    Pp[(wv*16 + quad*4 + reg)*VT_STR + dt*16 + colL] = f2b(o[dt][reg]*inv[reg]);
  {
    int rr = lane >> 2;              // 0..15 row within strip
    int cc = (lane & 3) * 16;        // 16-wide d chunk
    const u16* crow = Pp + (wv*16 + rr)*VT_STR + cc;
    short8 c0 = *(const short8*)(crow);
    short8 c1 = *(const short8*)(crow + 8);
    u16* orow = ctxb + (size_t)(b*64 + wv*16 + rr)*256 + h*64 + cc;
    *(short8*)(orow)     = c0;
    *(short8*)(orow + 8) = c1;
  }
}

// ---------------- K5: oproj GEMM + residual + LN -> x1 f32 ----------------
__global__ __launch_bounds__(256,2) void k_oproj(const float* __restrict__ WF, const u16* __restrict__ ctxb,
                                                 const u16* __restrict__ x0b, const u16* __restrict__ WTO,
                                                 float* __restrict__ x1){
  __shared__ u16 As[32*264];
  __shared__ float Sred[4][32], Qred[4][32], Mrow[32], Rrow[32];
  long row0 = (long)blockIdx.x*32;
  stageA256(ctxb, row0, As);
  __syncthreads();
  int t = threadIdx.x;
  int lane = t & 63, wv = t >> 6;
  int colL = lane & 15, quad = lane >> 4;
  f32x4 acc[2][4] = {};
  mmK256(As, WTO, wv, colL, quad, lane, acc);
  float S[2][4] = {}, Q[2][4] = {};
#pragma unroll
  for(int ct=0; ct<4; ct++){
    int col = wv*64 + ct*16 + colL;
    float bc = WF[O_bo+col];
#pragma unroll
    for(int rt=0; rt<2; rt++)
#pragma unroll
    for(int reg=0; reg<4; reg++){
      int row = rt*16 + quad*4 + reg;
      float y = acc[rt][ct][reg] + bc + bf2f(x0b[(size_t)(row0+row)*256 + col]);
      acc[rt][ct][reg] = y;
      S[rt][reg] += y; Q[rt][reg] += y*y;
    }
  }
#pragma unroll
  for(int o=1;o<16;o<<=1)
#pragma unroll
  for(int rt=0;rt<2;rt++)
#pragma unroll
  for(int reg=0;reg<4;reg++){ S[rt][reg] += __shfl_xor(S[rt][reg],o); Q[rt][reg] += __shfl_xor(Q[rt][reg],o); }
  if(colL==0){
#pragma unroll
    for(int rt=0;rt<2;rt++)
#pragma unroll
    for(int reg=0;reg<4;reg++){
      Sred[wv][rt*16+quad*4+reg] = S[rt][reg];
      Qred[wv][rt*16+quad*4+reg] = Q[rt][reg];
    }
  }
  __syncthreads();
  if(t<32){
    float s = Sred[0][t]+Sred[1][t]+Sred[2][t]+Sred[3][t];
    float q = Qred[0][t]+Qred[1][t]+Qred[2][t]+Qred[3][t];
    float mean = s*(1.f/256.f);
    float var  = q*(1.f/256.f) - mean*mean;
    Mrow[t] = mean; Rrow[t] = rsqrtf(var + 1e-5f);
  }
  __syncthreads();
#pragma unroll
  for(int ct=0; ct<4; ct++){
    int col = wv*64 + ct*16 + colL;
    float gc = WF[O_ag+col], bc = WF[O_ab+col];
#pragma unroll
    for(int rt=0; rt<2; rt++)
#pragma unroll
    for(int reg=0; reg<4; reg++){
      int row = rt*16 + quad*4 + reg;
      x1[(size_t)(row0+row)*256 + col] = (acc[rt][ct][reg]-Mrow[row])*Rrow[row]*gc + bc;
    }
  }
}

// ---------------- K6: classifier GEMM, BM=64 / 4-pass K-split (B-traffic halved) ----------------
// R6/R8 analysis: per-block B-stream is 512KB regardless of loop tactics; 1024 blocks = 512MB L2,
// latency-bound at 37% occ (48us, MfmaUtil 13.7). Fix: BM=64 halves block count (256MB B traffic)
// while 4 passes of 256 K-cols keep LDS at 32KB (4 blocks/CU) and acc[4][4]=64 VGPR doubles
// per-wave MFMA density (16 MFMA per 4 B-loads). Pass slices match WTC layout:
// pass0=e [K 0,256), pass1=u, pass2=|d| (+LN stats, needs e&u), pass3=e*u.
// Lean unroll-1 staging targets VGPR <=128. Grid 512.
__global__ __launch_bounds__(256) void k_cls(const float* __restrict__ WF, const float* __restrict__ x1,
                                             const int* __restrict__ pairs, const u16* __restrict__ WTC,
                                             const float* __restrict__ UG, float* __restrict__ out){
  __shared__ u16 As[64*256];                   // 32 KB: one 256-col K-slice for 64 pairs
  __shared__ float rsS[64], mrsS[64];
  int t = threadIdx.x;
  int lane = t & 63, wv = t >> 6;
  int colL = lane & 15, quad = lane >> 4;
  int rxl = colL & 7;
  int r = t>>2, t4 = t&3, rx = r&7;
  long pr = (long)blockIdx.x*64 + r;
  int bb = (int)(pr>>7);
  int i0 = pairs[pr*2], i1 = pairs[pr*2+1];
  const float* ef = x1 + (size_t)(bb*64+i0)*256 + t4*64;
  const float* eu = x1 + (size_t)(bb*64+i1)*256 + t4*64;
  f32x4 acc[4][4] = {};
  float S = 0.f, Q = 0.f;
#pragma unroll 1
  for(int pass=0; pass<4; pass++){
#pragma unroll 1
    for(int c=0;c<8;c++){
      short8 f;
      if(pass==0){
        float e[8];
        *(float4*)(e)   = *(const float4*)(ef + c*8);
        *(float4*)(e+4) = *(const float4*)(ef + c*8 + 4);
#pragma unroll
        for(int j=0;j<8;j++) f[j] = (short)f2b(e[j]);
      } else if(pass==1){
        float u[8];
        *(float4*)(u)   = *(const float4*)(eu + c*8);
        *(float4*)(u+4) = *(const float4*)(eu + c*8 + 4);
#pragma unroll
        for(int j=0;j<8;j++) f[j] = (short)f2b(u[j]);
      } else if(pass==2){
        float e[8], u[8];
        *(float4*)(e)   = *(const float4*)(ef + c*8);
        *(float4*)(e+4) = *(const float4*)(ef + c*8 + 4);
        *(float4*)(u)   = *(const float4*)(eu + c*8);
        *(float4*)(u+4) = *(const float4*)(eu + c*8 + 4);
#pragma unroll
        for(int j=0;j<8;j++){
          float d = e[j]-u[j], p = e[j]*u[j];
          f[j] = (short)f2b(fabsf(d));
          S += 2.f*e[j] + fabsf(d) + p;
          Q += e[j]*e[j] + u[j]*u[j] + 2.f*d*d + p*p;
        }
      } else {
        float e[8], u[8];
        *(float4*)(e)   = *(const float4*)(ef + c*8);
        *(float4*)(e+4) = *(const float4*)(ef + c*8 + 4);
        *(float4*)(u)   = *(const float4*)(eu + c*8);
        *(float4*)(u+4) = *(const float4*)(eu + c*8 + 4);
#pragma unroll
        for(int j=0;j<8;j++) f[j] = (short)f2b(e[j]*u[j]);
      }
      int cc = t4*8 + c;               // 0..31 chunk within the 256-col slice
      *(short8*)(As + r*256 + (cc^rx)*8) = f;
    }
    if(pass==2){
      // uniform wave-collective reduction across the 4 lanes sharing a pair row
      S += __shfl_xor(S,1); S += __shfl_xor(S,2);
      Q += __shfl_xor(Q,1); Q += __shfl_xor(Q,2);
      if(t4==0){
        float mean = S*(1.f/1280.f);
        float var  = Q*(1.f/1280.f) - mean*mean;
        float rs = rsqrtf(var + 1e-5f);
        rsS[r] = rs; mrsS[r] = mean*rs;
      }
    }
    __syncthreads();
#pragma unroll 1
    for(int ks=0; ks<8; ks++){
      int kst = pass*8 + ks;
      short8 b0[4];
#pragma unroll
      for(int ct=0;ct<4;ct++)
        b0[ct] = *(const short8*)(WTC + (size_t)(((wv*4+ct)*32 + kst)*64 + lane)*8);
      short8 a[4];
#pragma unroll
      for(int rt=0;rt<4;rt++)
        a[rt] = *(short8*)(As + (colL + rt*16)*256 + ((ks*4+quad)^rxl)*8);
#pragma unroll
      for(int ct=0;ct<4;ct++)
#pragma unroll
      for(int rt=0;rt<4;rt++)
        acc[rt][ct] = MFMA(a[rt], b0[ct], acc[rt][ct]);
    }
    __syncthreads();
  }
  float plog[4][4] = {};
#pragma unroll
  for(int ct=0; ct<4; ct++){
    int col = wv*64 + ct*16 + colL;
    float Uc = UG[col], Gc = UG[256+col], w2 = WF[O_Wc2+col];
#pragma unroll
    for(int rt=0;rt<4;rt++)
#pragma unroll
    for(int reg=0;reg<4;reg++){
      int row = rt*16 + quad*4 + reg;
      float h = rsS[row]*acc[rt][ct][reg] - mrsS[row]*Gc + Uc;
      h = fmaxf(h, 0.f);
      plog[rt][reg] = fmaf(h, w2, plog[rt][reg]);
    }
  }
#pragma unroll
  for(int o=1;o<16;o<<=1)
#pragma unroll
  for(int rt=0;rt<4;rt++)
#pragma unroll
  for(int reg=0;reg<4;reg++) plog[rt][reg] += __shfl_xor(plog[rt][reg], o);
  float* red = (float*)As;
  if(colL==0){
#pragma unroll
    for(int rt=0;rt<4;rt++)
#pragma unroll
    for(int reg=0;reg<4;reg++) red[wv*64 + rt*16 + quad*4 + reg] = plog[rt][reg];
  }
  __syncthreads();
  if(t<64){
    float l = red[t] + red[64+t] + red[128+t] + red[192+t] + WF[O_bc2];
    out[(long)blockIdx.x*64 + t] = l;
  }
}

// ---------------- workspace layout (bytes) ----------------
#define WS_MASK   3145728u
#define WS_POOLED 3211264u
#define WS_UG     3473408u
#define WS_WT     4194304u
#define WS_WTC    4980736u
#define WS_H      6291456u
#define WS_X0     14680064u
#define WS_Q      23068672u
#define WS_CTX    48234496u
#define WS_X1     56623104u
// total 73,400,320 B (~70 MiB)

extern "C" void kernel_launch(void* const* d_in, const int* in_sizes, int n_in,
                              void* d_out, int out_size, void* d_ws, size_t ws_size,
                              hipStream_t stream){
  char* ws = (char*)d_ws;
  float* WF     = (float*)ws;
  int*   maskI  = (int*)  (ws + WS_MASK);
  float* pooled = (float*)(ws + WS_POOLED);
  float* UG     = (float*)(ws + WS_UG);
  u16*   WT     = (u16*)  (ws + WS_WT);      // 6 x [256][256] bf16 (fragment-major)
  u16*   WTC    = (u16*)  (ws + WS_WTC);     // [256][1024] bf16 (fragment-major)
  u16*   hb     = (u16*)  (ws + WS_H);
  u16*   x0b    = (u16*)  (ws + WS_X0);
  u16*   qkvb   = (u16*)  (ws + WS_Q);       // 3 x [16384][256] bf16
  u16*   ctxb   = (u16*)  (ws + WS_CTX);
  float* x1     = (float*)(ws + WS_X1);

  WPar wp;
  for(int i=0;i<25;i++) wp.src[i] = d_in[4+i];
  wp.traj = (const u32*)d_in[0];
  wp.dst  = WF;

  const int* roles  = (const int*)d_in[1];
  const int* pairs  = (const int*)d_in[2];
  const u32* mraw   = (const u32*)d_in[3];
  float* out = (float*)d_out;

  hipLaunchKernelGGL(k_init,  dim3(NCONV+256), dim3(256), 0, stream, wp, mraw, pooled, maskI);
  hipLaunchKernelGGL(k_wprep, dim3(4512), dim3(256), 0, stream, WF, pooled, roles, (u32*)hb, WT, WTC, UG);
  hipLaunchKernelGGL(k_enc2,  dim3(512),  dim3(256), 0, stream, WF, hb, roles, maskI,
                     WT + 0*65536, WT + 1*65536, x0b);
  hipLaunchKernelGGL(k_qkv,   dim3(512,3),dim3(256), 0, stream, WF, x0b, WT + 2*65536, qkvb);
  hipLaunchKernelGGL(k_attn6, dim3(256,4),dim3(256), 0, stream,
                     qkvb, qkvb + 4194304, qkvb + 2*4194304, maskI, ctxb);
  hipLaunchKernelGGL(k_oproj, dim3(512),  dim3(256), 0, stream, WF, ctxb, x0b, WT + 5*65536, x1);
  hipLaunchKernelGGL(k_cls,   dim3(512),  dim3(256), 0, stream, WF, x1, pairs, WTC, UG, out);
}

// Round 11
// 237.899 us; speedup vs baseline: 1.0939x; 1.0939x over previous
//
#include <hip/hip_runtime.h>
#include <hip/hip_bf16.h>

typedef unsigned int u32;
typedef unsigned short u16;
typedef __attribute__((ext_vector_type(8))) short short8;   // 8 bf16 (4 VGPRs)
typedef __attribute__((ext_vector_type(4))) float f32x4;    // 4 fp32 acc

#define MFMA(a,b,c) __builtin_amdgcn_mfma_f32_16x16x32_bf16(a,b,c,0,0,0)

// ---------------- helpers ----------------
__device__ __forceinline__ float bf2f(u16 u){ return __uint_as_float(((u32)u)<<16); }
__device__ __forceinline__ float lo16(u32 w){ return __uint_as_float(w<<16); }
__device__ __forceinline__ float hi16(u32 w){ return __uint_as_float(w & 0xffff0000u); }
__device__ __forceinline__ u16 f2b(float x){ __hip_bfloat16 h=__float2bfloat16(x); return *(u16*)&h; }
__device__ __forceinline__ u32 pack2(float a, float b){ return (u32)f2b(a) | ((u32)f2b(b)<<16); }

// canonical f32 weight pool: element offsets (verified R5)
#define O_Wf1 0
#define O_bf1 1024
#define O_Wf2 1280
#define O_bf2 66816
#define O_Wu1 67072
#define O_bu1 68096
#define O_Wu2 68352
#define O_bu2 133888
#define O_remb 134144
#define O_Wq 134656
#define O_bq 200192
#define O_Wk 200448
#define O_bk 265984
#define O_Wv 266240
#define O_bv 331776
#define O_Wo 332032
#define O_bo 397568
#define O_ag 397824
#define O_ab 398080
#define O_lg 398336
#define O_lb 399616
#define O_Wc1 400896
#define O_bc1 728576
#define O_Wc2 728832
#define O_bc2 729088
#define TOTW 729089
#define NCONV 2849   // ceil(TOTW/256)

static __device__ const int c_off[26] = {
  0,1024,1280,66816,67072,68096,68352,133888,134144,134656,200192,200448,
  265984,266240,331776,332032,397568,397824,398080,398336,399616,400896,
  728576,728832,729088,729089};

struct WPar { const void* src[25]; const u32* traj; float* dst; };

__device__ __forceinline__ int detect_bf16(const u32* traj){
  int inr = 0;
#pragma unroll 1
  for(int i=0;i<64;i++){
    u32 e = (traj[i]>>7) & 0xffu;
    inr += (e >= 0x58u && e <= 0x9au) ? 1 : 0;
  }
  return (inr==64) ? 1 : 0;
}

// ---------------- K0: conv (weights->f32) ∥ pool+mask, block-partitioned ----------------
__global__ __launch_bounds__(256) void k_init(WPar p, const u32* __restrict__ mraw,
                                              float* __restrict__ pooled, int* __restrict__ maskI){
  __shared__ int fl;
  if(threadIdx.x==0) fl = detect_bf16(p.traj);
  __syncthreads();
  int mode = fl;
  if(blockIdx.x < NCONV){
    int g = blockIdx.x*256 + threadIdx.x;
    if(g >= TOTW) return;
    int t = 0;
#pragma unroll 1
    for(int i=1;i<25;i++) if(g >= c_off[i]) t = i;
    int j = g - c_off[t];
    float v = mode ? bf2f(((const u16*)p.src[t])[j]) : ((const float*)p.src[t])[j];
    p.dst[g] = v;
  } else {
    int t = (blockIdx.x - NCONV)*256 + threadIdx.x;
    int b = t>>8, r = t&255;
    float s = 0.f;
    if(mode){
      const u16* tp = (const u16*)p.traj + (size_t)b*12800 + r;
#pragma unroll 1
      for(int l=0;l<50;l++) s += bf2f(tp[l*256]);
    } else {
      const float* tp = (const float*)p.traj + (size_t)b*12800 + r;
#pragma unroll 1
      for(int l=0;l<50;l++) s += tp[l*256];
    }
    pooled[t] = s * 0.02f;
    if(t < 16384){
      bool isByte = false;
#pragma unroll
      for(int w=0;w<16;w++) isByte |= (mraw[w] > 1u);
      int v;
      if(isByte){ u32 w = mraw[t>>2]; v = (int)((w >> ((t&3)*8)) & 0xffu); }
      else      { v = (int)mraw[t]; }
      maskI[t] = (v!=0) ? 1 : 0;
    }
  }
}

// ---------------- K1: merged WF-dependent prep: h(4096) | trans(96) | transc(64) | prep(256) ----------------
static __device__ const int t_src[6] = {O_Wf2, O_Wu2, O_Wq, O_Wk, O_Wv, O_Wo};
__global__ __launch_bounds__(256) void k_wprep(const float* __restrict__ WF, const float* __restrict__ pooled,
                                               const int* __restrict__ roles, u32* __restrict__ hb,
                                               u16* __restrict__ WT, u16* __restrict__ WTC,
                                               float* __restrict__ UG){
  __shared__ float tl[64][65];
  int bid = blockIdx.x;
  int t = threadIdx.x;
  if(bid < 4096){
    // ---- enc layer 1 -> h bf16 [16384][256] ----
    int g = bid*256 + t;
    int r = g>>6, e0 = (g&63)*4;
    float4 pl = *(const float4*)(pooled + r*4);
    int role = roles[r];
    const float* W1 = WF + (role ? O_Wu1 : O_Wf1);
    const float* b1 = WF + (role ? O_bu1 : O_bf1);
    float h[4];
#pragma unroll
    for(int c=0;c<4;c++){
      int e = e0+c;
      float v = b1[e] + pl.x*W1[e] + pl.y*W1[256+e] + pl.z*W1[512+e] + pl.w*W1[768+e];
      h[c] = fmaxf(v, 0.f);
    }
    hb[(r*256+e0)>>1]     = pack2(h[0],h[1]);
    hb[((r*256+e0)>>1)+1] = pack2(h[2],h[3]);
    return;
  }
  if(bid < 4192){
    // ---- transpose f32 -> bf16 WT in MFMA-fragment-major order ----
    int b2 = bid - 4096;
    int mat = b2 >> 4, tile = b2 & 15;
    int kt = (tile>>2)*64, nt = (tile&3)*64;
    int i = t>>2, c4 = (t&3)*16;
    const float* src = WF + t_src[mat] + (kt+i)*256 + nt + c4;
#pragma unroll
    for(int c=0;c<16;c+=4) *(float4*)&tl[i][c4+c] = *(const float4*)(src + c);
    __syncthreads();
    int n = nt + i;
    int tile_n = n >> 4, nl = n & 15;
    int ks = (kt + c4) >> 5;
    u16* base = WT + mat*65536;
#pragma unroll
    for(int h=0; h<2; h++){
      int quad = ((c4 + h*8) >> 3) & 3;
      short8 v;
#pragma unroll
      for(int j=0;j<8;j++) v[j] = (short)f2b(tl[c4 + h*8 + j][i]);
      *(short8*)(base + ((tile_n*8 + ks)*64 + quad*16 + nl)*8) = v;
    }
    return;
  }
  if(bid < 4256){
    // ---- WTC (lg-folded, d-combined Wc1^T, K=1024) fragment-major ----
    int b2 = bid - 4192;
    int seg = b2 >> 4, tile = b2 & 15;
    int jt = (tile>>2)*64, nt = (tile&3)*64;
    int i = t>>2, c4 = (t&3)*16;
    int j = jt + i;
#pragma unroll 1
    for(int c=0;c<16;c++){
      int n = nt + c4 + c;
      float v;
      if(seg==0)      v = WF[O_lg+j]*WF[O_Wc1 + j*256 + n] + WF[O_lg+768+j]*WF[O_Wc1 + (768+j)*256 + n];
      else if(seg==1) v = WF[O_lg+256+j]*WF[O_Wc1+(256+j)*256+n] - WF[O_lg+768+j]*WF[O_Wc1+(768+j)*256+n];
      else if(seg==2) v = WF[O_lg+512+j]*WF[O_Wc1+(512+j)*256+n];
      else            v = WF[O_lg+1024+j]*WF[O_Wc1+(1024+j)*256+n];
      tl[i][c4+c] = v;
    }
    __syncthreads();
    int n = nt + i;
    int tile_n = n >> 4, nl = n & 15;
    int kbase = seg*256 + jt + c4;
    int ks = kbase >> 5;
#pragma unroll
    for(int h=0; h<2; h++){
      int quad = ((kbase + h*8) >> 3) & 3;
      short8 v;
#pragma unroll
      for(int jj=0;jj<8;jj++) v[jj] = (short)f2b(tl[c4 + h*8 + jj][i]);
      *(short8*)(WTC + ((tile_n*32 + ks)*64 + quad*16 + nl)*8) = v;
    }
    return;
  }
  {
    // ---- U[n] / G[n] for classifier epilogue ----
    __shared__ float ru[4], rg[4];
    int n = bid - 4256;
    float u = 0.f, g = 0.f;
#pragma unroll
    for(int j=0;j<5;j++){
      int m = t + j*256;
      float w = WF[O_Wc1 + m*256 + n];
      u = fmaf(WF[O_lb+m], w, u);
      g = fmaf(WF[O_lg+m], w, g);
    }
#pragma unroll
    for(int o=32;o>0;o>>=1){ u += __shfl_xor(u,o,64); g += __shfl_xor(g,o,64); }
    int wv = t>>6;
    if((t&63)==0){ ru[wv]=u; rg[wv]=g; }
    __syncthreads();
    if(t==0){
      UG[n]     = ru[0]+ru[1]+ru[2]+ru[3] + WF[O_bc1+n];
      UG[256+n] = rg[0]+rg[1]+rg[2]+rg[3];
    }
  }
}

// ---------------- shared GEMM pieces (BM=32, K=256, LDS stride 264) ----------------
__device__ __forceinline__ void stageA256(const u16* __restrict__ A, long row0, u16* As){
  int t = threadIdx.x;
  int r = t >> 3, c0 = (t & 7) * 32;
  const u16* src = A + (row0 + r)*256 + c0;
  u16* dst = As + r*264 + c0;
#pragma unroll
  for(int i=0;i<4;i++) *(short8*)(dst + i*8) = *(const short8*)(src + i*8);
}

// B in fragment-major order: frag(tile,ks) at ((tile*8+ks)*64 + lane)*8 — 1KB coalesced/wave
__device__ __forceinline__ void mmK256(const u16* As, const u16* __restrict__ WT, int wv,
                                       int colL, int quad, int lane, f32x4 acc[2][4]){
#pragma unroll
  for(int ks=0; ks<8; ks++){
    short8 a0 = *(short8*)(As + colL*264 + ks*32 + quad*8);
    short8 a1 = *(short8*)(As + (colL+16)*264 + ks*32 + quad*8);
#pragma unroll
    for(int ct=0; ct<4; ct++){
      short8 b = *(const short8*)(WT + (((wv*4+ct)*8 + ks)*64 + lane)*8);
      acc[0][ct] = MFMA(a0, b, acc[0][ct]);
      acc[1][ct] = MFMA(a1, b, acc[1][ct]);
    }
  }
}

// ---------------- K2: FUSED enc layer 2 (dual GEMM + select/mask/remb -> x0) + QKV GEMMs ----------------
// k_qkv's A-tile is exactly the x0 rows this block computes -> keep them in LDS, skip 3x restage.
// x0 crosses barriers only as completed MFMA-result registers (k_oproj-verified pattern; no
// in-flight global loads cross a barrier — R7's failure mode avoided).
static __device__ const int qkv_b[3] = {O_bq, O_bk, O_bv};
__global__ __launch_bounds__(256,2) void k_encqkv(const float* __restrict__ WF, const u16* __restrict__ hb,
                                                  const int* __restrict__ roles, const int* __restrict__ maskI,
                                                  const u16* __restrict__ WT, u16* __restrict__ x0b,
                                                  u16* __restrict__ qkvb){
  __shared__ u16 As[32*264];
  __shared__ int roleS[32], maskS[32];
  long row0 = (long)blockIdx.x*32;
  int t = threadIdx.x;
  stageA256(hb, row0, As);
  if(t<32){ roleS[t]=roles[row0+t]; maskS[t]=maskI[row0+t]; }
  __syncthreads();
  int lane = t & 63, wv = t >> 6;
  int colL = lane & 15, quad = lane >> 4;
  f32x4 accF[2][4] = {};
  f32x4 accU[2][4] = {};
  mmK256(As, WT + 0*65536, wv, colL, quad, lane, accF);
  mmK256(As, WT + 1*65536, wv, colL, quad, lane, accU);
  // ---- x0 epilogue (into accF in place) + global write ----
#pragma unroll
  for(int ct=0; ct<4; ct++){
    int col = wv*64 + ct*16 + colL;
    float bfc = WF[O_bf2+col], buc = WF[O_bu2+col];
    float r0c = WF[O_remb+col], r1c = WF[O_remb+256+col];
#pragma unroll
    for(int rt=0; rt<2; rt++)
#pragma unroll
    for(int reg=0; reg<4; reg++){
      int row = rt*16 + quad*4 + reg;
      float vf = accF[rt][ct][reg] + bfc;
      float vu = accU[rt][ct][reg] + buc;
      int ro = roleS[row];
      float v = ro ? vu : vf;
      v = maskS[row] ? v : 0.f;
      v += ro ? r1c : r0c;
      accF[rt][ct][reg] = v;
      x0b[(size_t)(row0+row)*256 + col] = f2b(v);
    }
  }
  __syncthreads();                     // all waves done reading As (hb tile)
  // ---- stash x0 tile into As for the QKV GEMMs ----
#pragma unroll
  for(int ct=0; ct<4; ct++){
    int col = wv*64 + ct*16 + colL;
#pragma unroll
    for(int rt=0; rt<2; rt++)
#pragma unroll
    for(int reg=0; reg<4; reg++){
      int row = rt*16 + quad*4 + reg;
      As[row*264 + col] = f2b(accF[rt][ct][reg]);
    }
  }
  __syncthreads();
  // ---- QKV GEMMs from the in-LDS x0 tile ----
#pragma unroll 1
  for(int y=0; y<3; y++){
    f32x4 acc[2][4] = {};
    mmK256(As, WT + (2+y)*65536, wv, colL, quad, lane, acc);
    u16* outp = qkvb + (size_t)y*4194304;
    int bo = qkv_b[y];
#pragma unroll
    for(int ct=0; ct<4; ct++){
      int col = wv*64 + ct*16 + colL;
      float bc = WF[bo+col];
#pragma unroll
      for(int rt=0; rt<2; rt++)
#pragma unroll
      for(int reg=0; reg<4; reg++){
        int row = rt*16 + quad*4 + reg;
        outp[(size_t)(row0+row)*256 + col] = f2b(acc[rt][ct][reg] + bc);
      }
    }
  }
}

// ---------------- K4: MFMA attention (verified R1: 286->261) ----------------
#define VT_STR 72   // u16 stride, multiple of 8 -> 16B-aligned b128 reads
__global__ __launch_bounds__(256,2) void k_attn6(const u16* __restrict__ qb, const u16* __restrict__ kb,
                                                 const u16* __restrict__ vb, const int* __restrict__ maskI,
                                                 u16* __restrict__ ctxb){
  __shared__ u16 Vt[64*VT_STR];     // V^T: Vt[d][j]
  __shared__ u16 Pp[64*VT_STR];     // exp(S-m) bf16: Pp[q][j]; later reused per-wave for ctx repack
  __shared__ int maskS[64];
  const int t = threadIdx.x;
  const int b = blockIdx.x, h = blockIdx.y;
  const int lane = t & 63;
  const int wv = t >> 6;
  const int colL = lane & 15, quad = lane >> 4;

  // ---- stage V^T + mask (all threads) ----
  {
    int j  = t >> 2;                 // 0..63 key row
    int dc = (t & 3) * 16;           // 16-wide d chunk
    const u16* vr = vb + (size_t)(b*64 + j)*256 + h*64 + dc;
    uint4 w0 = *(const uint4*)(vr);
    uint4 w1 = *(const uint4*)(vr + 8);
    u32 wd[8] = {w0.x,w0.y,w0.z,w0.w,w1.x,w1.y,w1.z,w1.w};
#pragma unroll
    for(int i=0;i<8;i++){
      u32 w = wd[i];
      Vt[(dc + 2*i    )*VT_STR + j] = (u16)(w & 0xffffu);
      Vt[(dc + 2*i + 1)*VT_STR + j] = (u16)(w >> 16);
    }
    if(t < 64) maskS[t] = maskI[b*64 + t];
  }

  // ---- QK^T: 8 MFMAs, operands straight from global ----
  f32x4 acc[4] = {};                 // acc[tj]: S[wv*16+quad*4+reg][tj*16+colL]
  {
    const u16* qrow = qb + (size_t)(b*64 + wv*16 + colL)*256 + h*64 + quad*8;
#pragma unroll
    for(int ks=0; ks<2; ks++){
      short8 a = *(const short8*)(qrow + ks*32);
#pragma unroll
      for(int tj=0; tj<4; tj++){
        short8 bf = *(const short8*)(kb + (size_t)(b*64 + tj*16 + colL)*256 + h*64 + ks*32 + quad*8);
        acc[tj] = MFMA(a, bf, acc[tj]);
      }
    }
  }

  __syncthreads();                   // Vt + maskS ready

  // ---- scale + mask + softmax (rows spread over the 16 lanes sharing quad) ----
#pragma unroll
  for(int tj=0; tj<4; tj++){
    int mk = maskS[tj*16 + colL];
#pragma unroll
    for(int reg=0; reg<4; reg++)
      acc[tj][reg] = mk ? acc[tj][reg]*0.125f : -1e9f;
  }
  float m[4], sum[4];
#pragma unroll
  for(int reg=0; reg<4; reg++){
    float v = fmaxf(fmaxf(acc[0][reg],acc[1][reg]), fmaxf(acc[2][reg],acc[3][reg]));
    v = fmaxf(v, __shfl_xor(v,1,64));
    v = fmaxf(v, __shfl_xor(v,2,64));
    v = fmaxf(v, __shfl_xor(v,4,64));
    v = fmaxf(v, __shfl_xor(v,8,64));
    m[reg] = v;
    sum[reg] = 0.f;
  }
#pragma unroll
  for(int tj=0; tj<4; tj++)
#pragma unroll
  for(int reg=0; reg<4; reg++){
    float e = __expf(acc[tj][reg] - m[reg]);
    acc[tj][reg] = e;
    sum[reg] += e;
  }
#pragma unroll
  for(int reg=0; reg<4; reg++){
    float v = sum[reg];
    v += __shfl_xor(v,1,64); v += __shfl_xor(v,2,64);
    v += __shfl_xor(v,4,64); v += __shfl_xor(v,8,64);
    sum[reg] = v;
  }

  // ---- P (unnormalized) -> bf16 -> own wave's LDS strip (wave-local, no barrier) ----
#pragma unroll
  for(int tj=0; tj<4; tj++)
#pragma unroll
  for(int reg=0; reg<4; reg++)
    Pp[(wv*16 + quad*4 + reg)*VT_STR + tj*16 + colL] = f2b(acc[tj][reg]);

  // ---- PV: 8 MFMAs; A = P strip (b128), B = Vt rows (b128) ----
  f32x4 o[4] = {};                   // o[dt]: ctx[wv*16+quad*4+reg][dt*16+colL]
  {
    const u16* prow = Pp + (wv*16 + colL)*VT_STR + quad*8;
#pragma unroll
    for(int ks=0; ks<2; ks++){
      short8 a = *(const short8*)(prow + ks*32);
#pragma unroll
      for(int dt=0; dt<4; dt++){
        short8 bf = *(const short8*)(Vt + (dt*16 + colL)*VT_STR + ks*32 + quad*8);
        o[dt] = MFMA(a, bf, o[dt]);
      }
    }
  }

  // ---- normalize (f32) + repack via own LDS strip for coalesced stores ----
  float inv[4];
#pragma unroll
  for(int reg=0; reg<4; reg++) inv[reg] = 1.f/sum[reg];
#pragma unroll
  for(int dt=0; dt<4; dt++)
#pragma unroll
  for(int reg=0; reg<4; reg++)
    Pp[(wv*16 + quad*4 + reg)*VT_STR + dt*16 + colL] = f2b(o[dt][reg]*inv[reg]);
  {
    int rr = lane >> 2;              // 0..15 row within strip
    int cc = (lane & 3) * 16;        // 16-wide d chunk
    const u16* crow = Pp + (wv*16 + rr)*VT_STR + cc;
    short8 c0 = *(const short8*)(crow);
    short8 c1 = *(const short8*)(crow + 8);
    u16* orow = ctxb + (size_t)(b*64 + wv*16 + rr)*256 + h*64 + cc;
    *(short8*)(orow)     = c0;
    *(short8*)(orow + 8) = c1;
  }
}

// ---------------- K5: oproj GEMM + residual + LN -> x1 f32 ----------------
__global__ __launch_bounds__(256,2) void k_oproj(const float* __restrict__ WF, const u16* __restrict__ ctxb,
                                                 const u16* __restrict__ x0b, const u16* __restrict__ WTO,
                                                 float* __restrict__ x1){
  __shared__ u16 As[32*264];
  __shared__ float Sred[4][32], Qred[4][32], Mrow[32], Rrow[32];
  long row0 = (long)blockIdx.x*32;
  stageA256(ctxb, row0, As);
  __syncthreads();
  int t = threadIdx.x;
  int lane = t & 63, wv = t >> 6;
  int colL = lane & 15, quad = lane >> 4;
  f32x4 acc[2][4] = {};
  mmK256(As, WTO, wv, colL, quad, lane, acc);
  float S[2][4] = {}, Q[2][4] = {};
#pragma unroll
  for(int ct=0; ct<4; ct++){
    int col = wv*64 + ct*16 + colL;
    float bc = WF[O_bo+col];
#pragma unroll
    for(int rt=0; rt<2; rt++)
#pragma unroll
    for(int reg=0; reg<4; reg++){
      int row = rt*16 + quad*4 + reg;
      float y = acc[rt][ct][reg] + bc + bf2f(x0b[(size_t)(row0+row)*256 + col]);
      acc[rt][ct][reg] = y;
      S[rt][reg] += y; Q[rt][reg] += y*y;
    }
  }
#pragma unroll
  for(int o=1;o<16;o<<=1)
#pragma unroll
  for(int rt=0;rt<2;rt++)
#pragma unroll
  for(int reg=0;reg<4;reg++){ S[rt][reg] += __shfl_xor(S[rt][reg],o); Q[rt][reg] += __shfl_xor(Q[rt][reg],o); }
  if(colL==0){
#pragma unroll
    for(int rt=0;rt<2;rt++)
#pragma unroll
    for(int reg=0;reg<4;reg++){
      Sred[wv][rt*16+quad*4+reg] = S[rt][reg];
      Qred[wv][rt*16+quad*4+reg] = Q[rt][reg];
    }
  }
  __syncthreads();
  if(t<32){
    float s = Sred[0][t]+Sred[1][t]+Sred[2][t]+Sred[3][t];
    float q = Qred[0][t]+Qred[1][t]+Qred[2][t]+Qred[3][t];
    float mean = s*(1.f/256.f);
    float var  = q*(1.f/256.f) - mean*mean;
    Mrow[t] = mean; Rrow[t] = rsqrtf(var + 1e-5f);
  }
  __syncthreads();
#pragma unroll
  for(int ct=0; ct<4; ct++){
    int col = wv*64 + ct*16 + colL;
    float gc = WF[O_ag+col], bc = WF[O_ab+col];
#pragma unroll
    for(int rt=0; rt<2; rt++)
#pragma unroll
    for(int reg=0; reg<4; reg++){
      int row = rt*16 + quad*4 + reg;
      x1[(size_t)(row0+row)*256 + col] = (acc[rt][ct][reg]-Mrow[row])*Rrow[row]*gc + bc;
    }
  }
}

// ---------------- K6: classifier GEMM — EXACT R6-verified config (48us, 242 total) ----------------
// BM=32, grid 1024, fused LN stats, unroll-1 staging, no prefetch. All restructuring
// attempts (BM=64 R2/R10, waves4 R3, prefetch R5/R7, unroll2 R8) were neutral or worse.
__global__ __launch_bounds__(256) void k_cls(const float* __restrict__ WF, const float* __restrict__ x1,
                                             const int* __restrict__ pairs, const u16* __restrict__ WTC,
                                             const float* __restrict__ UG, float* __restrict__ out){
  __shared__ u16 As[32*512];                   // 32 KB; XOR-swizzled chunks of 8
  __shared__ float rsS[32], mrsS[32];
  int t = threadIdx.x;
  int lane = t & 63, wv = t >> 6;
  int colL = lane & 15, quad = lane >> 4;
  int rxl = colL & 7;
  int r = t>>3, t8 = t&7, rx = r&7;
  long pr = (long)blockIdx.x*32 + r;
  int bb = (int)(pr>>7);
  int i0 = pairs[pr*2], i1 = pairs[pr*2+1];
  const float* ef = x1 + (size_t)(bb*64+i0)*256 + t8*32;
  const float* eu = x1 + (size_t)(bb*64+i1)*256 + t8*32;
  f32x4 acc[2][4] = {};
  float S = 0.f, Q = 0.f;
#pragma unroll 1
  for(int pass=0; pass<2; pass++){
#pragma unroll 1
    for(int c=0;c<4;c++){
      float e[8], u[8];
      *(float4*)(e)   = *(const float4*)(ef + c*8);
      *(float4*)(e+4) = *(const float4*)(ef + c*8 + 4);
      *(float4*)(u)   = *(const float4*)(eu + c*8);
      *(float4*)(u+4) = *(const float4*)(eu + c*8 + 4);
      short8 f0, f1;
#pragma unroll
      for(int j=0;j<8;j++){
        float d = e[j]-u[j];
        if(pass==0){
          f0[j] = (short)f2b(e[j]);        f1[j] = (short)f2b(u[j]);
          float p = e[j]*u[j];
          S += 2.f*e[j] + fabsf(d) + p;
          Q += e[j]*e[j] + u[j]*u[j] + 2.f*d*d + p*p;
        } else {
          f0[j] = (short)f2b(fabsf(d));    f1[j] = (short)f2b(e[j]*u[j]);
        }
      }
      int cc = t8*4 + c;
      *(short8*)(As + r*512 + (( 0 + cc)^rx)*8) = f0;
      *(short8*)(As + r*512 + ((32 + cc)^rx)*8) = f1;
    }
    if(pass==0){
      S += __shfl_xor(S,1); S += __shfl_xor(S,2); S += __shfl_xor(S,4);
      Q += __shfl_xor(Q,1); Q += __shfl_xor(Q,2); Q += __shfl_xor(Q,4);
      if(t8==0){
        float mean = S*(1.f/1280.f);
        float var  = Q*(1.f/1280.f) - mean*mean;
        float rs = rsqrtf(var + 1e-5f);
        rsS[r] = rs; mrsS[r] = mean*rs;
      }
    }
    __syncthreads();
#pragma unroll 1
    for(int ks=0; ks<16; ks++){
      int kst = pass*16 + ks;
      short8 b0[4];
#pragma unroll
      for(int ct=0;ct<4;ct++)
        b0[ct] = *(const short8*)(WTC + (size_t)(((wv*4+ct)*32 + kst)*64 + lane)*8);
      short8 a0 = *(short8*)(As + colL*512      + ((ks*4+quad)^rxl)*8);
      short8 a1 = *(short8*)(As + (colL+16)*512 + ((ks*4+quad)^rxl)*8);
#pragma unroll
      for(int ct=0;ct<4;ct++){
        acc[0][ct] = MFMA(a0, b0[ct], acc[0][ct]);
        acc[1][ct] = MFMA(a1, b0[ct], acc[1][ct]);
      }
    }
    __syncthreads();
  }
  float plog[2][4] = {};
#pragma unroll
  for(int ct=0; ct<4; ct++){
    int col = wv*64 + ct*16 + colL;
    float Uc = UG[col], Gc = UG[256+col], w2 = WF[O_Wc2+col];
#pragma unroll
    for(int rt=0;rt<2;rt++)
#pragma unroll
    for(int reg=0;reg<4;reg++){
      int row = rt*16 + quad*4 + reg;
      float h = rsS[row]*acc[rt][ct][reg] - mrsS[row]*Gc + Uc;
      h = fmaxf(h, 0.f);
      plog[rt][reg] = fmaf(h, w2, plog[rt][reg]);
    }
  }
#pragma unroll
  for(int o=1;o<16;o<<=1)
#pragma unroll
  for(int rt=0;rt<2;rt++)
#pragma unroll
  for(int reg=0;reg<4;reg++) plog[rt][reg] += __shfl_xor(plog[rt][reg], o);
  float* red = (float*)As;
  if(colL==0){
#pragma unroll
    for(int rt=0;rt<2;rt++)
#pragma unroll
    for(int reg=0;reg<4;reg++) red[wv*32 + rt*16 + quad*4 + reg] = plog[rt][reg];
  }
  __syncthreads();
  if(t<32){
    float l = red[t] + red[32+t] + red[64+t] + red[96+t] + WF[O_bc2];
    out[(long)blockIdx.x*32 + t] = l;
  }
}

// ---------------- workspace layout (bytes) ----------------
#define WS_MASK   3145728u
#define WS_POOLED 3211264u
#define WS_UG     3473408u
#define WS_WT     4194304u
#define WS_WTC    4980736u
#define WS_H      6291456u
#define WS_X0     14680064u
#define WS_Q      23068672u
#define WS_CTX    48234496u
#define WS_X1     56623104u
// total 73,400,320 B (~70 MiB)

extern "C" void kernel_launch(void* const* d_in, const int* in_sizes, int n_in,
                              void* d_out, int out_size, void* d_ws, size_t ws_size,
                              hipStream_t stream){
  char* ws = (char*)d_ws;
  float* WF     = (float*)ws;
  int*   maskI  = (int*)  (ws + WS_MASK);
  float* pooled = (float*)(ws + WS_POOLED);
  float* UG     = (float*)(ws + WS_UG);
  u16*   WT     = (u16*)  (ws + WS_WT);      // 6 x [256][256] bf16 (fragment-major)
  u16*   WTC    = (u16*)  (ws + WS_WTC);     // [256][1024] bf16 (fragment-major)
  u16*   hb     = (u16*)  (ws + WS_H);
  u16*   x0b    = (u16*)  (ws + WS_X0);
  u16*   qkvb   = (u16*)  (ws + WS_Q);       // 3 x [16384][256] bf16
  u16*   ctxb   = (u16*)  (ws + WS_CTX);
  float* x1     = (float*)(ws + WS_X1);

  WPar wp;
  for(int i=0;i<25;i++) wp.src[i] = d_in[4+i];
  wp.traj = (const u32*)d_in[0];
  wp.dst  = WF;

  const int* roles  = (const int*)d_in[1];
  const int* pairs  = (const int*)d_in[2];
  const u32* mraw   = (const u32*)d_in[3];
  float* out = (float*)d_out;

  hipLaunchKernelGGL(k_init,   dim3(NCONV+256), dim3(256), 0, stream, wp, mraw, pooled, maskI);
  hipLaunchKernelGGL(k_wprep,  dim3(4512), dim3(256), 0, stream, WF, pooled, roles, (u32*)hb, WT, WTC, UG);
  hipLaunchKernelGGL(k_encqkv, dim3(512),  dim3(256), 0, stream, WF, hb, roles, maskI, WT, x0b, qkvb);
  hipLaunchKernelGGL(k_attn6,  dim3(256,4),dim3(256), 0, stream,
                     qkvb, qkvb + 4194304, qkvb + 2*4194304, maskI, ctxb);
  hipLaunchKernelGGL(k_oproj,  dim3(512),  dim3(256), 0, stream, WF, ctxb, x0b, WT + 5*65536, x1);
  hipLaunchKernelGGL(k_cls,    dim3(1024), dim3(256), 0, stream, WF, x1, pairs, WTC, UG, out);
}

// Round 12
// 222.084 us; speedup vs baseline: 1.1718x; 1.0712x over previous
//
#include <hip/hip_runtime.h>
#include <hip/hip_bf16.h>

typedef unsigned int u32;
typedef unsigned short u16;
typedef __attribute__((ext_vector_type(8))) short short8;   // 8 bf16 (4 VGPRs)
typedef __attribute__((ext_vector_type(4))) float f32x4;    // 4 fp32 acc

#define MFMA(a,b,c) __builtin_amdgcn_mfma_f32_16x16x32_bf16(a,b,c,0,0,0)

// ---------------- helpers ----------------
__device__ __forceinline__ float bf2f(u16 u){ return __uint_as_float(((u32)u)<<16); }
__device__ __forceinline__ float lo16(u32 w){ return __uint_as_float(w<<16); }
__device__ __forceinline__ float hi16(u32 w){ return __uint_as_float(w & 0xffff0000u); }
__device__ __forceinline__ u16 f2b(float x){ __hip_bfloat16 h=__float2bfloat16(x); return *(u16*)&h; }
__device__ __forceinline__ u32 pack2(float a, float b){ return (u32)f2b(a) | ((u32)f2b(b)<<16); }

// canonical f32 weight pool: element offsets (verified R5)
#define O_Wf1 0
#define O_bf1 1024
#define O_Wf2 1280
#define O_bf2 66816
#define O_Wu1 67072
#define O_bu1 68096
#define O_Wu2 68352
#define O_bu2 133888
#define O_remb 134144
#define O_Wq 134656
#define O_bq 200192
#define O_Wk 200448
#define O_bk 265984
#define O_Wv 266240
#define O_bv 331776
#define O_Wo 332032
#define O_bo 397568
#define O_ag 397824
#define O_ab 398080
#define O_lg 398336
#define O_lb 399616
#define O_Wc1 400896
#define O_bc1 728576
#define O_Wc2 728832
#define O_bc2 729088
#define TOTW 729089
#define NCONV 2849   // ceil(TOTW/256)

static __device__ const int c_off[26] = {
  0,1024,1280,66816,67072,68096,68352,133888,134144,134656,200192,200448,
  265984,266240,331776,332032,397568,397824,398080,398336,399616,400896,
  728576,728832,729088,729089};

struct WPar { const void* src[25]; const u32* traj; float* dst; };

__device__ __forceinline__ int detect_bf16(const u32* traj){
  int inr = 0;
#pragma unroll 1
  for(int i=0;i<64;i++){
    u32 e = (traj[i]>>7) & 0xffu;
    inr += (e >= 0x58u && e <= 0x9au) ? 1 : 0;
  }
  return (inr==64) ? 1 : 0;
}

// ---------------- K0: conv (weights->f32) ∥ pool+mask, block-partitioned ----------------
__global__ __launch_bounds__(256) void k_init(WPar p, const u32* __restrict__ mraw,
                                              float* __restrict__ pooled, int* __restrict__ maskI){
  __shared__ int fl;
  if(threadIdx.x==0) fl = detect_bf16(p.traj);
  __syncthreads();
  int mode = fl;
  if(blockIdx.x < NCONV){
    int g = blockIdx.x*256 + threadIdx.x;
    if(g >= TOTW) return;
    int t = 0;
#pragma unroll 1
    for(int i=1;i<25;i++) if(g >= c_off[i]) t = i;
    int j = g - c_off[t];
    float v = mode ? bf2f(((const u16*)p.src[t])[j]) : ((const float*)p.src[t])[j];
    p.dst[g] = v;
  } else {
    int t = (blockIdx.x - NCONV)*256 + threadIdx.x;
    int b = t>>8, r = t&255;
    float s = 0.f;
    if(mode){
      const u16* tp = (const u16*)p.traj + (size_t)b*12800 + r;
#pragma unroll 1
      for(int l=0;l<50;l++) s += bf2f(tp[l*256]);
    } else {
      const float* tp = (const float*)p.traj + (size_t)b*12800 + r;
#pragma unroll 1
      for(int l=0;l<50;l++) s += tp[l*256];
    }
    pooled[t] = s * 0.02f;
    if(t < 16384){
      bool isByte = false;
#pragma unroll
      for(int w=0;w<16;w++) isByte |= (mraw[w] > 1u);
      int v;
      if(isByte){ u32 w = mraw[t>>2]; v = (int)((w >> ((t&3)*8)) & 0xffu); }
      else      { v = (int)mraw[t]; }
      maskI[t] = (v!=0) ? 1 : 0;
    }
  }
}

// ---------------- K1: merged WF-dependent prep: h(4096) | trans(96) | transc(64) | prep(256) ----------------
static __device__ const int t_src[6] = {O_Wf2, O_Wu2, O_Wq, O_Wk, O_Wv, O_Wo};
__global__ __launch_bounds__(256) void k_wprep(const float* __restrict__ WF, const float* __restrict__ pooled,
                                               const int* __restrict__ roles, u32* __restrict__ hb,
                                               u16* __restrict__ WT, u16* __restrict__ WTC,
                                               float* __restrict__ UG){
  __shared__ float tl[64][65];
  int bid = blockIdx.x;
  int t = threadIdx.x;
  if(bid < 4096){
    // ---- enc layer 1 -> h bf16 [16384][256] ----
    int g = bid*256 + t;
    int r = g>>6, e0 = (g&63)*4;
    float4 pl = *(const float4*)(pooled + r*4);
    int role = roles[r];
    const float* W1 = WF + (role ? O_Wu1 : O_Wf1);
    const float* b1 = WF + (role ? O_bu1 : O_bf1);
    float h[4];
#pragma unroll
    for(int c=0;c<4;c++){
      int e = e0+c;
      float v = b1[e] + pl.x*W1[e] + pl.y*W1[256+e] + pl.z*W1[512+e] + pl.w*W1[768+e];
      h[c] = fmaxf(v, 0.f);
    }
    hb[(r*256+e0)>>1]     = pack2(h[0],h[1]);
    hb[((r*256+e0)>>1)+1] = pack2(h[2],h[3]);
    return;
  }
  if(bid < 4192){
    // ---- transpose f32 -> bf16 WT in MFMA-fragment-major order ----
    int b2 = bid - 4096;
    int mat = b2 >> 4, tile = b2 & 15;
    int kt = (tile>>2)*64, nt = (tile&3)*64;
    int i = t>>2, c4 = (t&3)*16;
    const float* src = WF + t_src[mat] + (kt+i)*256 + nt + c4;
#pragma unroll
    for(int c=0;c<16;c+=4) *(float4*)&tl[i][c4+c] = *(const float4*)(src + c);
    __syncthreads();
    int n = nt + i;
    int tile_n = n >> 4, nl = n & 15;
    int ks = (kt + c4) >> 5;
    u16* base = WT + mat*65536;
#pragma unroll
    for(int h=0; h<2; h++){
      int quad = ((c4 + h*8) >> 3) & 3;
      short8 v;
#pragma unroll
      for(int j=0;j<8;j++) v[j] = (short)f2b(tl[c4 + h*8 + j][i]);
      *(short8*)(base + ((tile_n*8 + ks)*64 + quad*16 + nl)*8) = v;
    }
    return;
  }
  if(bid < 4256){
    // ---- WTC (lg-folded, d-combined Wc1^T, K=1024) fragment-major ----
    int b2 = bid - 4192;
    int seg = b2 >> 4, tile = b2 & 15;
    int jt = (tile>>2)*64, nt = (tile&3)*64;
    int i = t>>2, c4 = (t&3)*16;
    int j = jt + i;
#pragma unroll 1
    for(int c=0;c<16;c++){
      int n = nt + c4 + c;
      float v;
      if(seg==0)      v = WF[O_lg+j]*WF[O_Wc1 + j*256 + n] + WF[O_lg+768+j]*WF[O_Wc1 + (768+j)*256 + n];
      else if(seg==1) v = WF[O_lg+256+j]*WF[O_Wc1+(256+j)*256+n] - WF[O_lg+768+j]*WF[O_Wc1+(768+j)*256+n];
      else if(seg==2) v = WF[O_lg+512+j]*WF[O_Wc1+(512+j)*256+n];
      else            v = WF[O_lg+1024+j]*WF[O_Wc1+(1024+j)*256+n];
      tl[i][c4+c] = v;
    }
    __syncthreads();
    int n = nt + i;
    int tile_n = n >> 4, nl = n & 15;
    int kbase = seg*256 + jt + c4;
    int ks = kbase >> 5;
#pragma unroll
    for(int h=0; h<2; h++){
      int quad = ((kbase + h*8) >> 3) & 3;
      short8 v;
#pragma unroll
      for(int jj=0;jj<8;jj++) v[jj] = (short)f2b(tl[c4 + h*8 + jj][i]);
      *(short8*)(WTC + ((tile_n*32 + ks)*64 + quad*16 + nl)*8) = v;
    }
    return;
  }
  {
    // ---- U[n] / G[n] for classifier epilogue ----
    __shared__ float ru[4], rg[4];
    int n = bid - 4256;
    float u = 0.f, g = 0.f;
#pragma unroll
    for(int j=0;j<5;j++){
      int m = t + j*256;
      float w = WF[O_Wc1 + m*256 + n];
      u = fmaf(WF[O_lb+m], w, u);
      g = fmaf(WF[O_lg+m], w, g);
    }
#pragma unroll
    for(int o=32;o>0;o>>=1){ u += __shfl_xor(u,o,64); g += __shfl_xor(g,o,64); }
    int wv = t>>6;
    if((t&63)==0){ ru[wv]=u; rg[wv]=g; }
    __syncthreads();
    if(t==0){
      UG[n]     = ru[0]+ru[1]+ru[2]+ru[3] + WF[O_bc1+n];
      UG[256+n] = rg[0]+rg[1]+rg[2]+rg[3];
    }
  }
}

// ---------------- shared GEMM pieces (BM=32, K=256, LDS stride 264) ----------------
__device__ __forceinline__ void stageA256(const u16* __restrict__ A, long row0, u16* As){
  int t = threadIdx.x;
  int r = t >> 3, c0 = (t & 7) * 32;
  const u16* src = A + (row0 + r)*256 + c0;
  u16* dst = As + r*264 + c0;
#pragma unroll
  for(int i=0;i<4;i++) *(short8*)(dst + i*8) = *(const short8*)(src + i*8);
}

// B in fragment-major order: frag(tile,ks) at ((tile*8+ks)*64 + lane)*8 — 1KB coalesced/wave
__device__ __forceinline__ void mmK256(const u16* As, const u16* __restrict__ WT, int wv,
                                       int colL, int quad, int lane, f32x4 acc[2][4]){
#pragma unroll
  for(int ks=0; ks<8; ks++){
    short8 a0 = *(short8*)(As + colL*264 + ks*32 + quad*8);
    short8 a1 = *(short8*)(As + (colL+16)*264 + ks*32 + quad*8);
#pragma unroll
    for(int ct=0; ct<4; ct++){
      short8 b = *(const short8*)(WT + (((wv*4+ct)*8 + ks)*64 + lane)*8);
      acc[0][ct] = MFMA(a0, b, acc[0][ct]);
      acc[1][ct] = MFMA(a1, b, acc[1][ct]);
    }
  }
}

// ---------------- K2: FUSED enc layer 2 + QKV GEMMs (verified R11: 242->238) ----------------
static __device__ const int qkv_b[3] = {O_bq, O_bk, O_bv};
__global__ __launch_bounds__(256,2) void k_encqkv(const float* __restrict__ WF, const u16* __restrict__ hb,
                                                  const int* __restrict__ roles, const int* __restrict__ maskI,
                                                  const u16* __restrict__ WT, u16* __restrict__ x0b,
                                                  u16* __restrict__ qkvb){
  __shared__ u16 As[32*264];
  __shared__ int roleS[32], maskS[32];
  long row0 = (long)blockIdx.x*32;
  int t = threadIdx.x;
  stageA256(hb, row0, As);
  if(t<32){ roleS[t]=roles[row0+t]; maskS[t]=maskI[row0+t]; }
  __syncthreads();
  int lane = t & 63, wv = t >> 6;
  int colL = lane & 15, quad = lane >> 4;
  f32x4 accF[2][4] = {};
  f32x4 accU[2][4] = {};
  mmK256(As, WT + 0*65536, wv, colL, quad, lane, accF);
  mmK256(As, WT + 1*65536, wv, colL, quad, lane, accU);
  // ---- x0 epilogue (into accF in place) + global write ----
#pragma unroll
  for(int ct=0; ct<4; ct++){
    int col = wv*64 + ct*16 + colL;
    float bfc = WF[O_bf2+col], buc = WF[O_bu2+col];
    float r0c = WF[O_remb+col], r1c = WF[O_remb+256+col];
#pragma unroll
    for(int rt=0; rt<2; rt++)
#pragma unroll
    for(int reg=0; reg<4; reg++){
      int row = rt*16 + quad*4 + reg;
      float vf = accF[rt][ct][reg] + bfc;
      float vu = accU[rt][ct][reg] + buc;
      int ro = roleS[row];
      float v = ro ? vu : vf;
      v = maskS[row] ? v : 0.f;
      v += ro ? r1c : r0c;
      accF[rt][ct][reg] = v;
      x0b[(size_t)(row0+row)*256 + col] = f2b(v);
    }
  }
  __syncthreads();                     // all waves done reading As (hb tile)
  // ---- stash x0 tile into As for the QKV GEMMs ----
#pragma unroll
  for(int ct=0; ct<4; ct++){
    int col = wv*64 + ct*16 + colL;
#pragma unroll
    for(int rt=0; rt<2; rt++)
#pragma unroll
    for(int reg=0; reg<4; reg++){
      int row = rt*16 + quad*4 + reg;
      As[row*264 + col] = f2b(accF[rt][ct][reg]);
    }
  }
  __syncthreads();
  // ---- QKV GEMMs from the in-LDS x0 tile ----
#pragma unroll 1
  for(int y=0; y<3; y++){
    f32x4 acc[2][4] = {};
    mmK256(As, WT + (2+y)*65536, wv, colL, quad, lane, acc);
    u16* outp = qkvb + (size_t)y*4194304;
    int bo = qkv_b[y];
#pragma unroll
    for(int ct=0; ct<4; ct++){
      int col = wv*64 + ct*16 + colL;
      float bc = WF[bo+col];
#pragma unroll
      for(int rt=0; rt<2; rt++)
#pragma unroll
      for(int reg=0; reg<4; reg++){
        int row = rt*16 + quad*4 + reg;
        outp[(size_t)(row0+row)*256 + col] = f2b(acc[rt][ct][reg] + bc);
      }
    }
  }
}

// ---------------- K4: MFMA attention (verified R1: 286->261) ----------------
#define VT_STR 72   // u16 stride, multiple of 8 -> 16B-aligned b128 reads
__global__ __launch_bounds__(256,2) void k_attn6(const u16* __restrict__ qb, const u16* __restrict__ kb,
                                                 const u16* __restrict__ vb, const int* __restrict__ maskI,
                                                 u16* __restrict__ ctxb){
  __shared__ u16 Vt[64*VT_STR];     // V^T: Vt[d][j]
  __shared__ u16 Pp[64*VT_STR];     // exp(S-m) bf16: Pp[q][j]; later reused per-wave for ctx repack
  __shared__ int maskS[64];
  const int t = threadIdx.x;
  const int b = blockIdx.x, h = blockIdx.y;
  const int lane = t & 63;
  const int wv = t >> 6;
  const int colL = lane & 15, quad = lane >> 4;

  // ---- stage V^T + mask (all threads) ----
  {
    int j  = t >> 2;                 // 0..63 key row
    int dc = (t & 3) * 16;           // 16-wide d chunk
    const u16* vr = vb + (size_t)(b*64 + j)*256 + h*64 + dc;
    uint4 w0 = *(const uint4*)(vr);
    uint4 w1 = *(const uint4*)(vr + 8);
    u32 wd[8] = {w0.x,w0.y,w0.z,w0.w,w1.x,w1.y,w1.z,w1.w};
#pragma unroll
    for(int i=0;i<8;i++){
      u32 w = wd[i];
      Vt[(dc + 2*i    )*VT_STR + j] = (u16)(w & 0xffffu);
      Vt[(dc + 2*i + 1)*VT_STR + j] = (u16)(w >> 16);
    }
    if(t < 64) maskS[t] = maskI[b*64 + t];
  }

  // ---- QK^T: 8 MFMAs, operands straight from global ----
  f32x4 acc[4] = {};                 // acc[tj]: S[wv*16+quad*4+reg][tj*16+colL]
  {
    const u16* qrow = qb + (size_t)(b*64 + wv*16 + colL)*256 + h*64 + quad*8;
#pragma unroll
    for(int ks=0; ks<2; ks++){
      short8 a = *(const short8*)(qrow + ks*32);
#pragma unroll
      for(int tj=0; tj<4; tj++){
        short8 bf = *(const short8*)(kb + (size_t)(b*64 + tj*16 + colL)*256 + h*64 + ks*32 + quad*8);
        acc[tj] = MFMA(a, bf, acc[tj]);
      }
    }
  }

  __syncthreads();                   // Vt + maskS ready

  // ---- scale + mask + softmax (rows spread over the 16 lanes sharing quad) ----
#pragma unroll
  for(int tj=0; tj<4; tj++){
    int mk = maskS[tj*16 + colL];
#pragma unroll
    for(int reg=0; reg<4; reg++)
      acc[tj][reg] = mk ? acc[tj][reg]*0.125f : -1e9f;
  }
  float m[4], sum[4];
#pragma unroll
  for(int reg=0; reg<4; reg++){
    float v = fmaxf(fmaxf(acc[0][reg],acc[1][reg]), fmaxf(acc[2][reg],acc[3][reg]));
    v = fmaxf(v, __shfl_xor(v,1,64));
    v = fmaxf(v, __shfl_xor(v,2,64));
    v = fmaxf(v, __shfl_xor(v,4,64));
    v = fmaxf(v, __shfl_xor(v,8,64));
    m[reg] = v;
    sum[reg] = 0.f;
  }
#pragma unroll
  for(int tj=0; tj<4; tj++)
#pragma unroll
  for(int reg=0; reg<4; reg++){
    float e = __expf(acc[tj][reg] - m[reg]);
    acc[tj][reg] = e;
    sum[reg] += e;
  }
#pragma unroll
  for(int reg=0; reg<4; reg++){
    float v = sum[reg];
    v += __shfl_xor(v,1,64); v += __shfl_xor(v,2,64);
    v += __shfl_xor(v,4,64); v += __shfl_xor(v,8,64);
    sum[reg] = v;
  }

  // ---- P (unnormalized) -> bf16 -> own wave's LDS strip (wave-local, no barrier) ----
#pragma unroll
  for(int tj=0; tj<4; tj++)
#pragma unroll
  for(int reg=0; reg<4; reg++)
    Pp[(wv*16 + quad*4 + reg)*VT_STR + tj*16 + colL] = f2b(acc[tj][reg]);

  // ---- PV: 8 MFMAs; A = P strip (b128), B = Vt rows (b128) ----
  f32x4 o[4] = {};                   // o[dt]: ctx[wv*16+quad*4+reg][dt*16+colL]
  {
    const u16* prow = Pp + (wv*16 + colL)*VT_STR + quad*8;
#pragma unroll
    for(int ks=0; ks<2; ks++){
      short8 a = *(const short8*)(prow + ks*32);
#pragma unroll
      for(int dt=0; dt<4; dt++){
        short8 bf = *(const short8*)(Vt + (dt*16 + colL)*VT_STR + ks*32 + quad*8);
        o[dt] = MFMA(a, bf, o[dt]);
      }
    }
  }

  // ---- normalize (f32) + repack via own LDS strip for coalesced stores ----
  float inv[4];
#pragma unroll
  for(int reg=0; reg<4; reg++) inv[reg] = 1.f/sum[reg];
#pragma unroll
  for(int dt=0; dt<4; dt++)
#pragma unroll
  for(int reg=0; reg<4; reg++)
    Pp[(wv*16 + quad*4 + reg)*VT_STR + dt*16 + colL] = f2b(o[dt][reg]*inv[reg]);
  {
    int rr = lane >> 2;              // 0..15 row within strip
    int cc = (lane & 3) * 16;        // 16-wide d chunk
    const u16* crow = Pp + (wv*16 + rr)*VT_STR + cc;
    short8 c0 = *(const short8*)(crow);
    short8 c1 = *(const short8*)(crow + 8);
    u16* orow = ctxb + (size_t)(b*64 + wv*16 + rr)*256 + h*64 + cc;
    *(short8*)(orow)     = c0;
    *(short8*)(orow + 8) = c1;
  }
}

// ---------------- K5: oproj GEMM + residual + LN -> x1 bf16 ----------------
// x1 stored as bf16: halves k_cls's gather traffic; e,u classifier features are
// bit-identical (they were f2b(x1) anyway); only |d|, e*u, and LN stats see
// bf16-rounded inputs (estimated absmax 0.004 -> ~0.006-0.008, under 0.0106 thr).
__global__ __launch_bounds__(256,2) void k_oproj(const float* __restrict__ WF, const u16* __restrict__ ctxb,
                                                 const u16* __restrict__ x0b, const u16* __restrict__ WTO,
                                                 u16* __restrict__ x1){
  __shared__ u16 As[32*264];
  __shared__ float Sred[4][32], Qred[4][32], Mrow[32], Rrow[32];
  long row0 = (long)blockIdx.x*32;
  stageA256(ctxb, row0, As);
  __syncthreads();
  int t = threadIdx.x;
  int lane = t & 63, wv = t >> 6;
  int colL = lane & 15, quad = lane >> 4;
  f32x4 acc[2][4] = {};
  mmK256(As, WTO, wv, colL, quad, lane, acc);
  float S[2][4] = {}, Q[2][4] = {};
#pragma unroll
  for(int ct=0; ct<4; ct++){
    int col = wv*64 + ct*16 + colL;
    float bc = WF[O_bo+col];
#pragma unroll
    for(int rt=0; rt<2; rt++)
#pragma unroll
    for(int reg=0; reg<4; reg++){
      int row = rt*16 + quad*4 + reg;
      float y = acc[rt][ct][reg] + bc + bf2f(x0b[(size_t)(row0+row)*256 + col]);
      acc[rt][ct][reg] = y;
      S[rt][reg] += y; Q[rt][reg] += y*y;
    }
  }
#pragma unroll
  for(int o=1;o<16;o<<=1)
#pragma unroll
  for(int rt=0;rt<2;rt++)
#pragma unroll
  for(int reg=0;reg<4;reg++){ S[rt][reg] += __shfl_xor(S[rt][reg],o); Q[rt][reg] += __shfl_xor(Q[rt][reg],o); }
  if(colL==0){
#pragma unroll
    for(int rt=0;rt<2;rt++)
#pragma unroll
    for(int reg=0;reg<4;reg++){
      Sred[wv][rt*16+quad*4+reg] = S[rt][reg];
      Qred[wv][rt*16+quad*4+reg] = Q[rt][reg];
    }
  }
  __syncthreads();
  if(t<32){
    float s = Sred[0][t]+Sred[1][t]+Sred[2][t]+Sred[3][t];
    float q = Qred[0][t]+Qred[1][t]+Qred[2][t]+Qred[3][t];
    float mean = s*(1.f/256.f);
    float var  = q*(1.f/256.f) - mean*mean;
    Mrow[t] = mean; Rrow[t] = rsqrtf(var + 1e-5f);
  }
  __syncthreads();
#pragma unroll
  for(int ct=0; ct<4; ct++){
    int col = wv*64 + ct*16 + colL;
    float gc = WF[O_ag+col], bc = WF[O_ab+col];
#pragma unroll
    for(int rt=0; rt<2; rt++)
#pragma unroll
    for(int reg=0; reg<4; reg++){
      int row = rt*16 + quad*4 + reg;
      x1[(size_t)(row0+row)*256 + col] = f2b((acc[rt][ct][reg]-Mrow[row])*Rrow[row]*gc + bc);
    }
  }
}

// ---------------- K6: classifier GEMM — R6-verified schedule, bf16 x1 gather ----------------
// BM=32, grid 1024, fused LN stats, unroll-1 staging (schedule unchanged from the
// verified 48us config). x1 now bf16: pass-0 features are raw copies; stats/d/p
// compute from bf2f (shift-only) converts. FETCH ~52 -> ~36 MB.
__global__ __launch_bounds__(256) void k_cls(const float* __restrict__ WF, const u16* __restrict__ x1,
                                             const int* __restrict__ pairs, const u16* __restrict__ WTC,
                                             const float* __restrict__ UG, float* __restrict__ out){
  __shared__ u16 As[32*512];                   // 32 KB; XOR-swizzled chunks of 8
  __shared__ float rsS[32], mrsS[32];
  int t = threadIdx.x;
  int lane = t & 63, wv = t >> 6;
  int colL = lane & 15, quad = lane >> 4;
  int rxl = colL & 7;
  int r = t>>3, t8 = t&7, rx = r&7;
  long pr = (long)blockIdx.x*32 + r;
  int bb = (int)(pr>>7);
  int i0 = pairs[pr*2], i1 = pairs[pr*2+1];
  const u16* ef = x1 + (size_t)(bb*64+i0)*256 + t8*32;
  const u16* eu = x1 + (size_t)(bb*64+i1)*256 + t8*32;
  f32x4 acc[2][4] = {};
  float S = 0.f, Q = 0.f;
#pragma unroll 1
  for(int pass=0; pass<2; pass++){
#pragma unroll 1
    for(int c=0;c<4;c++){
      short8 ev = *(const short8*)(ef + c*8);
      short8 uv = *(const short8*)(eu + c*8);
      short8 f0, f1;
#pragma unroll
      for(int j=0;j<8;j++){
        float e = bf2f((u16)ev[j]);
        float u = bf2f((u16)uv[j]);
        float d = e-u;
        if(pass==0){
          f0[j] = ev[j];  f1[j] = uv[j];
          float p = e*u;
          S += 2.f*e + fabsf(d) + p;
          Q += e*e + u*u + 2.f*d*d + p*p;
        } else {
          f0[j] = (short)f2b(fabsf(d));  f1[j] = (short)f2b(e*u);
        }
      }
      int cc = t8*4 + c;
      *(short8*)(As + r*512 + (( 0 + cc)^rx)*8) = f0;
      *(short8*)(As + r*512 + ((32 + cc)^rx)*8) = f1;
    }
    if(pass==0){
      S += __shfl_xor(S,1); S += __shfl_xor(S,2); S += __shfl_xor(S,4);
      Q += __shfl_xor(Q,1); Q += __shfl_xor(Q,2); Q += __shfl_xor(Q,4);
      if(t8==0){
        float mean = S*(1.f/1280.f);
        float var  = Q*(1.f/1280.f) - mean*mean;
        float rs = rsqrtf(var + 1e-5f);
        rsS[r] = rs; mrsS[r] = mean*rs;
      }
    }
    __syncthreads();
#pragma unroll 1
    for(int ks=0; ks<16; ks++){
      int kst = pass*16 + ks;
      short8 b0[4];
#pragma unroll
      for(int ct=0;ct<4;ct++)
        b0[ct] = *(const short8*)(WTC + (size_t)(((wv*4+ct)*32 + kst)*64 + lane)*8);
      short8 a0 = *(short8*)(As + colL*512      + ((ks*4+quad)^rxl)*8);
      short8 a1 = *(short8*)(As + (colL+16)*512 + ((ks*4+quad)^rxl)*8);
#pragma unroll
      for(int ct=0;ct<4;ct++){
        acc[0][ct] = MFMA(a0, b0[ct], acc[0][ct]);
        acc[1][ct] = MFMA(a1, b0[ct], acc[1][ct]);
      }
    }
    __syncthreads();
  }
  float plog[2][4] = {};
#pragma unroll
  for(int ct=0; ct<4; ct++){
    int col = wv*64 + ct*16 + colL;
    float Uc = UG[col], Gc = UG[256+col], w2 = WF[O_Wc2+col];
#pragma unroll
    for(int rt=0;rt<2;rt++)
#pragma unroll
    for(int reg=0;reg<4;reg++){
      int row = rt*16 + quad*4 + reg;
      float h = rsS[row]*acc[rt][ct][reg] - mrsS[row]*Gc + Uc;
      h = fmaxf(h, 0.f);
      plog[rt][reg] = fmaf(h, w2, plog[rt][reg]);
    }
  }
#pragma unroll
  for(int o=1;o<16;o<<=1)
#pragma unroll
  for(int rt=0;rt<2;rt++)
#pragma unroll
  for(int reg=0;reg<4;reg++) plog[rt][reg] += __shfl_xor(plog[rt][reg], o);
  float* red = (float*)As;
  if(colL==0){
#pragma unroll
    for(int rt=0;rt<2;rt++)
#pragma unroll
    for(int reg=0;reg<4;reg++) red[wv*32 + rt*16 + quad*4 + reg] = plog[rt][reg];
  }
  __syncthreads();
  if(t<32){
    float l = red[t] + red[32+t] + red[64+t] + red[96+t] + WF[O_bc2];
    out[(long)blockIdx.x*32 + t] = l;
  }
}

// ---------------- workspace layout (bytes) ----------------
#define WS_MASK   3145728u
#define WS_POOLED 3211264u
#define WS_UG     3473408u
#define WS_WT     4194304u
#define WS_WTC    4980736u
#define WS_H      6291456u
#define WS_X0     14680064u
#define WS_Q      23068672u
#define WS_CTX    48234496u
#define WS_X1     56623104u
// total 73,400,320 B (~70 MiB); x1 now bf16 (uses half its slot)

extern "C" void kernel_launch(void* const* d_in, const int* in_sizes, int n_in,
                              void* d_out, int out_size, void* d_ws, size_t ws_size,
                              hipStream_t stream){
  char* ws = (char*)d_ws;
  float* WF     = (float*)ws;
  int*   maskI  = (int*)  (ws + WS_MASK);
  float* pooled = (float*)(ws + WS_POOLED);
  float* UG     = (float*)(ws + WS_UG);
  u16*   WT     = (u16*)  (ws + WS_WT);      // 6 x [256][256] bf16 (fragment-major)
  u16*   WTC    = (u16*)  (ws + WS_WTC);     // [256][1024] bf16 (fragment-major)
  u16*   hb     = (u16*)  (ws + WS_H);
  u16*   x0b    = (u16*)  (ws + WS_X0);
  u16*   qkvb   = (u16*)  (ws + WS_Q);       // 3 x [16384][256] bf16
  u16*   ctxb   = (u16*)  (ws + WS_CTX);
  u16*   x1     = (u16*)  (ws + WS_X1);      // bf16 [16384][256]

  WPar wp;
  for(int i=0;i<25;i++) wp.src[i] = d_in[4+i];
  wp.traj = (const u32*)d_in[0];
  wp.dst  = WF;

  const int* roles  = (const int*)d_in[1];
  const int* pairs  = (const int*)d_in[2];
  const u32* mraw   = (const u32*)d_in[3];
  float* out = (float*)d_out;

  hipLaunchKernelGGL(k_init,   dim3(NCONV+256), dim3(256), 0, stream, wp, mraw, pooled, maskI);
  hipLaunchKernelGGL(k_wprep,  dim3(4512), dim3(256), 0, stream, WF, pooled, roles, (u32*)hb, WT, WTC, UG);
  hipLaunchKernelGGL(k_encqkv, dim3(512),  dim3(256), 0, stream, WF, hb, roles, maskI, WT, x0b, qkvb);
  hipLaunchKernelGGL(k_attn6,  dim3(256,4),dim3(256), 0, stream,
                     qkvb, qkvb + 4194304, qkvb + 2*4194304, maskI, ctxb);
  hipLaunchKernelGGL(k_oproj,  dim3(512),  dim3(256), 0, stream, WF, ctxb, x0b, WT + 5*65536, x1);
  hipLaunchKernelGGL(k_cls,    dim3(1024), dim3(256), 0, stream, WF, x1, pairs, WTC, UG, out);
}